// Round 5
// baseline (211.313 us; speedup 1.0000x reference)
//
#include <hip/hip_runtime.h>
#include <hip/hip_bf16.h>

// SparseLinear forward exploiting ~50% zero rows of x:
//   1) compact_cvt_x: per-row zero detection; nonzero rows -> bf16 compacted A
//      (atomic ticket + rowmap); zero rows -> y[row] = bias directly.
//   2) gemm_cmp: C[Mc,N] = Acmp * W^T + bias, scattered to orig rows.
//      BM=BN=128, BK=64, 4 waves, 64 KiB LDS dbuf -> 2 blocks/CU (unsynced
//      block pairs overlap MFMA and LDS pipes), counted vmcnt(4), zero-conflict
//      XOR swizzle, early-exit blocks beyond compacted M.

typedef __bf16 bf16x8 __attribute__((ext_vector_type(8)));
typedef float f32x4 __attribute__((ext_vector_type(4)));

constexpr int Mfull = 4096;  // T*B
constexpr int Nn = 4096;     // C_OUT
constexpr int Kk = 4096;     // C_IN
constexpr int GBM = 128, GBN = 128, GBK = 64;
constexpr int GNT = Kk / GBK;          // 64 K-tiles
// dbuf = 16384 elems (32 KiB): [A_k0][A_k1][B_k0][B_k1], each [128 rows][32 k]
constexpr int GDBUF = 16384;
constexpr int GA0 = 0, GA1 = 4096, GB0 = 8192, GB1 = 12288;

__device__ int g_Mc;
__device__ int g_rowmap[Mfull];

__device__ __forceinline__ unsigned short f2bf_rne(float f) {
    unsigned int u = __float_as_uint(f);
    u += 0x7fffu + ((u >> 16) & 1u);   // round-to-nearest-even
    return (unsigned short)(u >> 16);
}

__global__ void reset_mc() {
    if (threadIdx.x == 0) g_Mc = 0;
}

// One block per row of x. Zero row -> write bias to out. Nonzero -> ticket,
// rowmap, bf16-convert into compacted Abf.
__global__ __launch_bounds__(256) void compact_cvt_x(
    const float* __restrict__ x, const float* __restrict__ bias,
    unsigned short* __restrict__ Abf, float* __restrict__ out)
{
    const int row = blockIdx.x;
    const int tid = threadIdx.x;
    const float4* xr = (const float4*)(x + (size_t)row * Kk);
    float4 v[4];
    bool nz = false;
#pragma unroll
    for (int i = 0; i < 4; ++i) {
        v[i] = xr[i * 256 + tid];
        nz = nz | (v[i].x != 0.f) | (v[i].y != 0.f) | (v[i].z != 0.f) | (v[i].w != 0.f);
    }
    __shared__ int s_flag, s_pos;
    if (tid == 0) s_flag = 0;
    __syncthreads();
    if (nz) s_flag = 1;
    __syncthreads();
    if (tid == 0 && s_flag) {
        const int p = atomicAdd(&g_Mc, 1);
        g_rowmap[p] = row;
        s_pos = p;
    }
    __syncthreads();
    if (s_flag) {
        unsigned short* dst = Abf + (size_t)s_pos * Kk;
#pragma unroll
        for (int i = 0; i < 4; ++i) {
            ushort4 r;
            r.x = f2bf_rne(v[i].x); r.y = f2bf_rne(v[i].y);
            r.z = f2bf_rne(v[i].z); r.w = f2bf_rne(v[i].w);
            *(ushort4*)(dst + i * 1024 + tid * 4) = r;
        }
    } else {
        const float4* bv = (const float4*)bias;
        float4* orow = (float4*)(out + (size_t)row * Nn);
#pragma unroll
        for (int i = 0; i < 4; ++i) orow[i * 256 + tid] = bv[i * 256 + tid];
    }
}

__global__ __launch_bounds__(256) void cvt_f32_bf16(const float* __restrict__ in,
                                                    unsigned short* __restrict__ out,
                                                    int n8) {
    int idx = blockIdx.x * blockDim.x + threadIdx.x;
    int stride = gridDim.x * blockDim.x;
    for (int i = idx; i < n8; i += stride) {
        long base = (long)i * 8;
        float4 v0 = *(const float4*)(in + base);
        float4 v1 = *(const float4*)(in + base + 4);
        ushort4 r0, r1;
        r0.x = f2bf_rne(v0.x); r0.y = f2bf_rne(v0.y);
        r0.z = f2bf_rne(v0.z); r0.w = f2bf_rne(v0.w);
        r1.x = f2bf_rne(v1.x); r1.y = f2bf_rne(v1.y);
        r1.z = f2bf_rne(v1.z); r1.w = f2bf_rne(v1.w);
        *(ushort4*)(out + base) = r0;
        *(ushort4*)(out + base + 4) = r1;
    }
}

// Stage one [128 rows][32 k] unit (8 KiB) via 2 global_load_lds per thread.
// Linear LDS dest; pre-swizzled global source: cg ^= (row>>1)&3.
__device__ __forceinline__ void stage_u128(const unsigned short* __restrict__ g,
                                           size_t grow0, int kcol0,
                                           unsigned short* unitbase,
                                           int tid, int wave) {
#pragma unroll
    for (int i = 0; i < 2; ++i) {
        const int row = i * 64 + (tid >> 2);
        const int cg  = (tid & 3) ^ ((row >> 1) & 3);
        const unsigned short* src = g + (grow0 + (size_t)row) * (size_t)Kk
                                      + (size_t)(kcol0 + cg * 8);
        unsigned short* dst = unitbase + i * 2048 + wave * 512;
        __builtin_amdgcn_global_load_lds(
            (const __attribute__((address_space(1))) void*)src,
            (__attribute__((address_space(3))) void*)dst, 16, 0, 0);
    }
}

__global__ __launch_bounds__(256, 2) void gemm_cmp(
    const unsigned short* __restrict__ A,   // [Mc][K] compacted bf16
    const unsigned short* __restrict__ B,   // [N][K] bf16
    const float* __restrict__ bias,         // [N]
    float* __restrict__ C)                  // [Mfull][N] fp32 (scatter target)
{
    __shared__ unsigned short lds[2 * GDBUF];   // 64 KiB -> 2 blocks/CU

    const int Mc = *(volatile int*)&g_Mc;

    // XCD-aware bijective swizzle: 1024 wgs, 1024 % 8 == 0
    const int wg = blockIdx.x;
    const int s  = ((wg & 7) << 7) | (wg >> 3);
    const int bm = s >> 5, bn = s & 31;
    if (bm * GBM >= Mc) return;      // beyond compacted M: early exit

    const size_t brow = (size_t)bm * GBM;
    const size_t bcol = (size_t)bn * GBN;

    const int tid  = threadIdx.x;
    const int wave = tid >> 6;
    const int lane = tid & 63;
    const int wr = wave >> 1;       // 0..1 (64 rows each)
    const int wc = wave & 1;        // 0..1 (64 cols each)
    const int lr = lane & 15;
    const int kg = lane >> 4;

    const int a_row0 = wr * 64 + lr;
    const int b_row0 = wc * 64 + lr;
    const int aoff = a_row0 * 32 + ((kg ^ ((a_row0 >> 1) & 3)) << 3);
    const int boff = b_row0 * 32 + ((kg ^ ((b_row0 >> 1) & 3)) << 3);

    f32x4 acc[4][4];
#pragma unroll
    for (int m = 0; m < 4; ++m)
#pragma unroll
        for (int n = 0; n < 4; ++n)
            acc[m][n] = (f32x4){0.f, 0.f, 0.f, 0.f};

    // ---- prologue: stage tile 0's 4 units (8 loads) ----
    stage_u128(A, brow, 0,  lds + GA0, tid, wave);
    stage_u128(B, bcol, 0,  lds + GB0, tid, wave);
    stage_u128(A, brow, 32, lds + GA1, tid, wave);
    stage_u128(B, bcol, 32, lds + GB1, tid, wave);
    asm volatile("s_waitcnt vmcnt(4)" ::: "memory");   // A_k0,B_k0 landed
    __builtin_amdgcn_s_barrier();

    for (int t = 0; t < GNT; ++t) {
        unsigned short* db = lds + (t & 1) * GDBUF;
        unsigned short* pb = lds + ((t & 1) ^ 1) * GDBUF;
        const int ktn = (t + 1) * GBK;
        const bool pf = (t + 1) < GNT;

        bf16x8 a[4], b[4];

        // ===== phase k0 =====
#pragma unroll
        for (int n = 0; n < 4; ++n) b[n] = *(const bf16x8*)(db + GB0 + boff + n * 512);
#pragma unroll
        for (int m = 0; m < 4; ++m) a[m] = *(const bf16x8*)(db + GA0 + aoff + m * 512);
        if (pf) {
            stage_u128(A, brow, ktn, pb + GA0, tid, wave);
            stage_u128(B, bcol, ktn, pb + GB0, tid, wave);
        }
        __builtin_amdgcn_s_barrier();
        asm volatile("s_waitcnt lgkmcnt(0)" ::: "memory");
        __builtin_amdgcn_sched_barrier(0);
        __builtin_amdgcn_s_setprio(1);
#pragma unroll
        for (int m = 0; m < 4; ++m)
#pragma unroll
            for (int n = 0; n < 4; ++n)
                acc[m][n] = __builtin_amdgcn_mfma_f32_16x16x32_bf16(
                    a[m], b[n], acc[m][n], 0, 0, 0);
        __builtin_amdgcn_s_setprio(0);
        // drain A_k1,B_k1(t) (oldest 4); keep A_k0,B_k0(t+1) in flight
        if (pf) { asm volatile("s_waitcnt vmcnt(4)" ::: "memory"); }
        else    { asm volatile("s_waitcnt vmcnt(0)" ::: "memory"); }
        __builtin_amdgcn_s_barrier();

        // ===== phase k1 =====
#pragma unroll
        for (int n = 0; n < 4; ++n) b[n] = *(const bf16x8*)(db + GB1 + boff + n * 512);
#pragma unroll
        for (int m = 0; m < 4; ++m) a[m] = *(const bf16x8*)(db + GA1 + aoff + m * 512);
        if (pf) {
            stage_u128(A, brow, ktn + 32, pb + GA1, tid, wave);
            stage_u128(B, bcol, ktn + 32, pb + GB1, tid, wave);
        }
        __builtin_amdgcn_s_barrier();
        asm volatile("s_waitcnt lgkmcnt(0)" ::: "memory");
        __builtin_amdgcn_sched_barrier(0);
        __builtin_amdgcn_s_setprio(1);
#pragma unroll
        for (int m = 0; m < 4; ++m)
#pragma unroll
            for (int n = 0; n < 4; ++n)
                acc[m][n] = __builtin_amdgcn_mfma_f32_16x16x32_bf16(
                    a[m], b[n], acc[m][n], 0, 0, 0);
        __builtin_amdgcn_s_setprio(0);
        // drain A_k0,B_k0(t+1); keep A_k1,B_k1(t+1) in flight
        if (pf) {
            asm volatile("s_waitcnt vmcnt(4)" ::: "memory");
            __builtin_amdgcn_s_barrier();
        }
    }

    // ---- epilogue: scatter via rowmap, mask rows >= Mc; fused bias ----
    float bsv[4];
#pragma unroll
    for (int n = 0; n < 4; ++n) bsv[n] = bias[bcol + wc * 64 + n * 16 + lr];
    const int rbase = bm * GBM + wr * 64 + kg * 4;
#pragma unroll
    for (int m = 0; m < 4; ++m) {
        const int r0 = rbase + m * 16;
#pragma unroll
        for (int j = 0; j < 4; ++j) {
            const int r = r0 + j;
            if (r < Mc) {
                const size_t orow = (size_t)g_rowmap[r] * (size_t)Nn;
#pragma unroll
                for (int n = 0; n < 4; ++n) {
                    C[orow + bcol + wc * 64 + n * 16 + lr] = acc[m][n][j] + bsv[n];
                }
            }
        }
    }
}

extern "C" void kernel_launch(void* const* d_in, const int* in_sizes, int n_in,
                              void* d_out, int out_size, void* d_ws, size_t ws_size,
                              hipStream_t stream) {
    const float* x    = (const float*)d_in[0];   // [T,B,C_IN] = [M,K]
    const float* w    = (const float*)d_in[1];   // [C_OUT,C_IN] = [N,K]
    const float* bias = (const float*)d_in[2];   // [N]
    float* out = (float*)d_out;                  // [M,N]

    unsigned short* Abf = (unsigned short*)d_ws;           // 32 MiB (compacted)
    unsigned short* Bbf = Abf + (size_t)Mfull * Kk;        // 32 MiB

    reset_mc<<<1, 64, 0, stream>>>();
    compact_cvt_x<<<Mfull, 256, 0, stream>>>(x, bias, Abf, out);
    const int n8 = (Nn * Kk) / 8;
    cvt_f32_bf16<<<2048, 256, 0, stream>>>(w, Bbf, n8);
    gemm_cmp<<<dim3((Mfull / GBM) * (Nn / GBN)), 256, 0, stream>>>(Abf, Bbf, bias, out);
}

// Round 6
// 170.550 us; speedup vs baseline: 1.2390x; 1.2390x over previous
//
#include <hip/hip_runtime.h>
#include <hip/hip_bf16.h>

// SparseLinear forward exploiting ~50% zero rows of x:
//   1) compact_cvt_x: per-row zero detection; nonzero rows -> bf16 compacted A
//      (atomic ticket + rowmap); zero rows -> y[row] = bias directly.
//   2) gemm_cmp: C[Mc,N] = Acmp * W^T + bias, scattered to orig rows.
//      BM=BN=128, BK=64, 4 waves, 64 KiB LDS dbuf -> 2 blocks/CU.
//      R5 bug fixed: early-exit blocks now spread across XCDs; bijective
//      XCD swizzle applied WITHIN the active range only (m204 formula).

typedef __bf16 bf16x8 __attribute__((ext_vector_type(8)));
typedef float f32x4 __attribute__((ext_vector_type(4)));

constexpr int Mfull = 4096;  // T*B
constexpr int Nn = 4096;     // C_OUT
constexpr int Kk = 4096;     // C_IN
constexpr int GBM = 128, GBN = 128, GBK = 64;
constexpr int GNT = Kk / GBK;          // 64 K-tiles
// dbuf = 16384 elems (32 KiB): [A_k0][A_k1][B_k0][B_k1], each [128 rows][32 k]
constexpr int GDBUF = 16384;
constexpr int GA0 = 0, GA1 = 4096, GB0 = 8192, GB1 = 12288;

__device__ int g_Mc;
__device__ int g_rowmap[Mfull];

__device__ __forceinline__ unsigned short f2bf_rne(float f) {
    unsigned int u = __float_as_uint(f);
    u += 0x7fffu + ((u >> 16) & 1u);   // round-to-nearest-even
    return (unsigned short)(u >> 16);
}

__global__ void reset_mc() {
    if (threadIdx.x == 0) g_Mc = 0;
}

// One block per row of x. Zero row -> write bias to out. Nonzero -> ticket,
// rowmap, bf16-convert into compacted Abf.
__global__ __launch_bounds__(256) void compact_cvt_x(
    const float* __restrict__ x, const float* __restrict__ bias,
    unsigned short* __restrict__ Abf, float* __restrict__ out)
{
    const int row = blockIdx.x;
    const int tid = threadIdx.x;
    const float4* xr = (const float4*)(x + (size_t)row * Kk);
    float4 v[4];
    bool nz = false;
#pragma unroll
    for (int i = 0; i < 4; ++i) {
        v[i] = xr[i * 256 + tid];
        nz = nz | (v[i].x != 0.f) | (v[i].y != 0.f) | (v[i].z != 0.f) | (v[i].w != 0.f);
    }
    __shared__ int s_flag, s_pos;
    if (tid == 0) s_flag = 0;
    __syncthreads();
    if (nz) s_flag = 1;
    __syncthreads();
    if (tid == 0 && s_flag) {
        const int p = atomicAdd(&g_Mc, 1);
        g_rowmap[p] = row;
        s_pos = p;
    }
    __syncthreads();
    if (s_flag) {
        unsigned short* dst = Abf + (size_t)s_pos * Kk;
#pragma unroll
        for (int i = 0; i < 4; ++i) {
            ushort4 r;
            r.x = f2bf_rne(v[i].x); r.y = f2bf_rne(v[i].y);
            r.z = f2bf_rne(v[i].z); r.w = f2bf_rne(v[i].w);
            *(ushort4*)(dst + i * 1024 + tid * 4) = r;
        }
    } else {
        const float4* bv = (const float4*)bias;
        float4* orow = (float4*)(out + (size_t)row * Nn);
#pragma unroll
        for (int i = 0; i < 4; ++i) orow[i * 256 + tid] = bv[i * 256 + tid];
    }
}

__global__ __launch_bounds__(256) void cvt_f32_bf16(const float* __restrict__ in,
                                                    unsigned short* __restrict__ out,
                                                    int n8) {
    int idx = blockIdx.x * blockDim.x + threadIdx.x;
    int stride = gridDim.x * blockDim.x;
    for (int i = idx; i < n8; i += stride) {
        long base = (long)i * 8;
        float4 v0 = *(const float4*)(in + base);
        float4 v1 = *(const float4*)(in + base + 4);
        ushort4 r0, r1;
        r0.x = f2bf_rne(v0.x); r0.y = f2bf_rne(v0.y);
        r0.z = f2bf_rne(v0.z); r0.w = f2bf_rne(v0.w);
        r1.x = f2bf_rne(v1.x); r1.y = f2bf_rne(v1.y);
        r1.z = f2bf_rne(v1.z); r1.w = f2bf_rne(v1.w);
        *(ushort4*)(out + base) = r0;
        *(ushort4*)(out + base + 4) = r1;
    }
}

// Stage one [128 rows][32 k] unit (8 KiB) via 2 global_load_lds per thread.
// Linear LDS dest; pre-swizzled global source: cg ^= (row>>1)&3.
__device__ __forceinline__ void stage_u128(const unsigned short* __restrict__ g,
                                           size_t grow0, int kcol0,
                                           unsigned short* unitbase,
                                           int tid, int wave) {
#pragma unroll
    for (int i = 0; i < 2; ++i) {
        const int row = i * 64 + (tid >> 2);
        const int cg  = (tid & 3) ^ ((row >> 1) & 3);
        const unsigned short* src = g + (grow0 + (size_t)row) * (size_t)Kk
                                      + (size_t)(kcol0 + cg * 8);
        unsigned short* dst = unitbase + i * 2048 + wave * 512;
        __builtin_amdgcn_global_load_lds(
            (const __attribute__((address_space(1))) void*)src,
            (__attribute__((address_space(3))) void*)dst, 16, 0, 0);
    }
}

__global__ __launch_bounds__(256, 2) void gemm_cmp(
    const unsigned short* __restrict__ A,   // [Mc][K] compacted bf16
    const unsigned short* __restrict__ B,   // [N][K] bf16
    const float* __restrict__ bias,         // [N]
    float* __restrict__ C)                  // [Mfull][N] fp32 (scatter target)
{
    __shared__ unsigned short lds[2 * GDBUF];   // 64 KiB -> 2 blocks/CU

    const int Mc = *(volatile int*)&g_Mc;
    const int nbm  = (Mc + GBM - 1) / GBM;      // active bm rows
    const int nact = nbm * (Nn / GBN);          // active tiles

    const int wg = blockIdx.x;
    if (wg >= nact) return;   // exits spread evenly across XCDs (wg round-robin)

    // m204 bijective XCD swizzle within [0, nact): each XCD gets a
    // contiguous chunk of tile-space (A-panel L2 locality per XCD).
    const int xcd = wg & 7;
    const int idx = wg >> 3;
    const int q = nact >> 3, r = nact & 7;
    const int s = (xcd < r ? xcd * (q + 1) : r * (q + 1) + (xcd - r) * q) + idx;
    const int bm = s >> 5, bn = s & 31;

    const size_t brow = (size_t)bm * GBM;
    const size_t bcol = (size_t)bn * GBN;

    const int tid  = threadIdx.x;
    const int wave = tid >> 6;
    const int lane = tid & 63;
    const int wr = wave >> 1;       // 0..1 (64 rows each)
    const int wc = wave & 1;        // 0..1 (64 cols each)
    const int lr = lane & 15;
    const int kg = lane >> 4;

    const int a_row0 = wr * 64 + lr;
    const int b_row0 = wc * 64 + lr;
    const int aoff = a_row0 * 32 + ((kg ^ ((a_row0 >> 1) & 3)) << 3);
    const int boff = b_row0 * 32 + ((kg ^ ((b_row0 >> 1) & 3)) << 3);

    f32x4 acc[4][4];
#pragma unroll
    for (int m = 0; m < 4; ++m)
#pragma unroll
        for (int n = 0; n < 4; ++n)
            acc[m][n] = (f32x4){0.f, 0.f, 0.f, 0.f};

    // ---- prologue: stage tile 0's 4 units (8 loads) ----
    stage_u128(A, brow, 0,  lds + GA0, tid, wave);
    stage_u128(B, bcol, 0,  lds + GB0, tid, wave);
    stage_u128(A, brow, 32, lds + GA1, tid, wave);
    stage_u128(B, bcol, 32, lds + GB1, tid, wave);
    asm volatile("s_waitcnt vmcnt(4)" ::: "memory");   // A_k0,B_k0 landed
    __builtin_amdgcn_s_barrier();

    for (int t = 0; t < GNT; ++t) {
        unsigned short* db = lds + (t & 1) * GDBUF;
        unsigned short* pb = lds + ((t & 1) ^ 1) * GDBUF;
        const int ktn = (t + 1) * GBK;
        const bool pf = (t + 1) < GNT;

        bf16x8 a[4], b[4];

        // ===== phase k0 =====
#pragma unroll
        for (int n = 0; n < 4; ++n) b[n] = *(const bf16x8*)(db + GB0 + boff + n * 512);
#pragma unroll
        for (int m = 0; m < 4; ++m) a[m] = *(const bf16x8*)(db + GA0 + aoff + m * 512);
        if (pf) {
            stage_u128(A, brow, ktn, pb + GA0, tid, wave);
            stage_u128(B, bcol, ktn, pb + GB0, tid, wave);
        }
        __builtin_amdgcn_s_barrier();
        asm volatile("s_waitcnt lgkmcnt(0)" ::: "memory");
        __builtin_amdgcn_sched_barrier(0);
        __builtin_amdgcn_s_setprio(1);
#pragma unroll
        for (int m = 0; m < 4; ++m)
#pragma unroll
            for (int n = 0; n < 4; ++n)
                acc[m][n] = __builtin_amdgcn_mfma_f32_16x16x32_bf16(
                    a[m], b[n], acc[m][n], 0, 0, 0);
        __builtin_amdgcn_s_setprio(0);
        // drain A_k1,B_k1(t) (oldest 4); keep A_k0,B_k0(t+1) in flight
        if (pf) { asm volatile("s_waitcnt vmcnt(4)" ::: "memory"); }
        else    { asm volatile("s_waitcnt vmcnt(0)" ::: "memory"); }
        __builtin_amdgcn_s_barrier();

        // ===== phase k1 =====
#pragma unroll
        for (int n = 0; n < 4; ++n) b[n] = *(const bf16x8*)(db + GB1 + boff + n * 512);
#pragma unroll
        for (int m = 0; m < 4; ++m) a[m] = *(const bf16x8*)(db + GA1 + aoff + m * 512);
        if (pf) {
            stage_u128(A, brow, ktn + 32, pb + GA1, tid, wave);
            stage_u128(B, bcol, ktn + 32, pb + GB1, tid, wave);
        }
        __builtin_amdgcn_s_barrier();
        asm volatile("s_waitcnt lgkmcnt(0)" ::: "memory");
        __builtin_amdgcn_sched_barrier(0);
        __builtin_amdgcn_s_setprio(1);
#pragma unroll
        for (int m = 0; m < 4; ++m)
#pragma unroll
            for (int n = 0; n < 4; ++n)
                acc[m][n] = __builtin_amdgcn_mfma_f32_16x16x32_bf16(
                    a[m], b[n], acc[m][n], 0, 0, 0);
        __builtin_amdgcn_s_setprio(0);
        // drain A_k0,B_k0(t+1); keep A_k1,B_k1(t+1) in flight
        if (pf) {
            asm volatile("s_waitcnt vmcnt(4)" ::: "memory");
            __builtin_amdgcn_s_barrier();
        }
    }

    // ---- epilogue: scatter via rowmap, mask rows >= Mc; fused bias ----
    float bsv[4];
#pragma unroll
    for (int n = 0; n < 4; ++n) bsv[n] = bias[bcol + wc * 64 + n * 16 + lr];
    const int rbase = bm * GBM + wr * 64 + kg * 4;
#pragma unroll
    for (int m = 0; m < 4; ++m) {
        const int r0 = rbase + m * 16;
#pragma unroll
        for (int j = 0; j < 4; ++j) {
            const int rr = r0 + j;
            if (rr < Mc) {
                const size_t orow = (size_t)g_rowmap[rr] * (size_t)Nn;
#pragma unroll
                for (int n = 0; n < 4; ++n) {
                    C[orow + bcol + wc * 64 + n * 16 + lr] = acc[m][n][j] + bsv[n];
                }
            }
        }
    }
}

extern "C" void kernel_launch(void* const* d_in, const int* in_sizes, int n_in,
                              void* d_out, int out_size, void* d_ws, size_t ws_size,
                              hipStream_t stream) {
    const float* x    = (const float*)d_in[0];   // [T,B,C_IN] = [M,K]
    const float* w    = (const float*)d_in[1];   // [C_OUT,C_IN] = [N,K]
    const float* bias = (const float*)d_in[2];   // [N]
    float* out = (float*)d_out;                  // [M,N]

    unsigned short* Abf = (unsigned short*)d_ws;           // 32 MiB (compacted)
    unsigned short* Bbf = Abf + (size_t)Mfull * Kk;        // 32 MiB

    reset_mc<<<1, 64, 0, stream>>>();
    compact_cvt_x<<<Mfull, 256, 0, stream>>>(x, bias, Abf, out);
    const int n8 = (Nn * Kk) / 8;
    cvt_f32_bf16<<<2048, 256, 0, stream>>>(w, Bbf, n8);
    gemm_cmp<<<dim3((Mfull / GBM) * (Nn / GBN)), 256, 0, stream>>>(Abf, Bbf, bias, out);
}